// Round 7
// baseline (792.535 us; speedup 1.0000x reference)
//
#include <hip/hip_runtime.h>
#include <hip/hip_bf16.h>

// GraphConvNormRelu: y = einsum('bctu,puv,poc->botv', x, A*g, W) + sum_p b;
// train-mode BN over (B,T,V); relu; +x residual.  B=32, C=64, T=512, V=54, P=4.
//
// R8 structure (blocked x tiles -> aligned contiguous pass1 reads):
//   R7 diagnosis: pass1's 108B-row reads at 110KB stride touch ~1.84 128B
//   sectors each -> 2.07x FETCH; the miss storm evicts cast's dirty xbf
//   lines from L3 -> their writebacks billed to pass1 (2.13x WRITE).
//   Fix: k_cast_blk writes x as xblk[bid][q][c][54] bf16 - each pass1
//   block's input is ONE contiguous 16B-aligned 13824B tile (same bytes
//   as xbf -> same proven workspace budget). pass1 stages it with a
//   4-round linear uint4 copy; A-frags read packed Xs via dword loads
//   (elements beyond u=54 multiply Ae's zero columns). Direct stores
//   (Ys dropped - R2 proved stores are clean when reads are clean);
//   LDS 47.7KB -> 3 blocks/CU.
//   k_pass2_lin / ypre layout / k_prep / k_finalize / fallback unchanged.

typedef __bf16 bf16_t;
typedef __bf16 bf16x8 __attribute__((ext_vector_type(8)));
typedef __bf16 bf16x4 __attribute__((ext_vector_type(4)));
typedef float  f32x4  __attribute__((ext_vector_type(4)));
typedef unsigned int uint32;

static __device__ __forceinline__ f32x4 mfma16(bf16x8 a, bf16x8 b, f32x4 c) {
  return __builtin_amdgcn_mfma_f32_16x16x32_bf16(a, b, c, 0, 0, 0);
}
static __device__ __forceinline__ uint32 pk2(float a, float b) {
  union { __bf16 h; unsigned short u; } ua, ub;
  ua.h = (__bf16)a; ub.h = (__bf16)b;
  return (uint32)ua.u | ((uint32)ub.u << 16);
}
static __device__ __forceinline__ float bflo(uint32 u) {
  union { uint32 u; float f; } r; r.u = u << 16; return r.f;
}
static __device__ __forceinline__ float bfhi(uint32 u) {
  union { uint32 u; float f; } r; r.u = u & 0xffff0000u; return r.f;
}

// ---------------- k_prep ----------------
__global__ __launch_bounds__(256) void k_prep(
    const float* __restrict__ A, const float* __restrict__ g,
    const float* __restrict__ W, const float* __restrict__ bias,
    bf16_t* __restrict__ W2, bf16_t* __restrict__ Ae,
    float* __restrict__ bsum, float* __restrict__ stats) {
  int i = blockIdx.x * 256 + threadIdx.x;
  if (i < 16384) {                       // W2[o][p*64+c] = W[p][o][c]
    int o = i >> 8, k = i & 255, p = k >> 6, c = k & 63;
    W2[i] = (bf16_t)W[p * 4096 + o * 64 + c];
  }
  if (i < 224 * 64) {                    // Ae[p*56+v][u] = A[p][u][v]*g[p][u][v]
    int pv = i >> 6, u = i & 63;
    int p = pv / 56, v = pv - p * 56;
    float val = 0.f;
    if (v < 54 && u < 54) {
      int idx = (p * 54 + u) * 54 + v;
      val = A[idx] * g[idx];
    }
    Ae[i] = (bf16_t)val;
  }
  if (i < 64) {
    float s = 0.f;
    for (int p = 0; p < 4; ++p) s += bias[p * 64 + i];
    bsum[i] = s;
  }
  if (i < 8192) stats[i] = 0.f;
}

// ---------------- k_cast_blk : x fp32 -> xblk[bid][q][c][54] bf16 ----------
// bid = b*256 + tg, tg = t/2.  Tile = 2*64*54 bf16 = 13824 B contiguous.
// Each block reads 64 rows of 432B (two adjacent t) and writes one dense tile.
__global__ __launch_bounds__(256) void k_cast_blk(const float* __restrict__ x,
                                                  bf16_t* __restrict__ xblk) {
  const int tid = threadIdx.x;
  const int bid = blockIdx.x;            // 8192
  const int b   = bid >> 8;
  const int t0  = (bid & 255) << 1;
  const float* xb = x + (size_t)b * 1769472;
  uint32* dstD = (uint32*)xblk + (size_t)bid * 3456;
  #pragma unroll
  for (int r = 0; r < 7; ++r) {
    int d = (r << 8) + tid;              // dword index within plane q=0
    if (d < 1728) {
      int c  = d / 27;
      int u2 = d - c * 27;
      const float* s = xb + (size_t)c * 27648 + (size_t)t0 * 54 + (u2 << 1);
      float2 a0 = *(const float2*)s;          // t = t0
      float2 a1 = *(const float2*)(s + 54);   // t = t0+1 (adjacent in memory)
      dstD[d]        = pk2(a0.x, a0.y);
      dstD[d + 1728] = pk2(a1.x, a1.y);
    }
  }
}

// ---------------- k_pass1_blk (primary) ----------------
#define ZS 264   // Zt row stride bf16 (256 K-vals + 8 pad); 132 dwords

__global__ __launch_bounds__(256, 3) void k_pass1_blk(
    const bf16_t* __restrict__ xblk, const bf16_t* __restrict__ W2,
    const bf16_t* __restrict__ Ae, const float* __restrict__ bsum,
    bf16_t* __restrict__ yprev, float* __restrict__ stats) {
  __shared__ __align__(16) bf16_t Xs[2 * 64 * 54 + 64];  // 13952 B (packed + pad)
  __shared__ bf16_t Zt[64 * ZS];                          // 33792 B  (47744 total)

  const int tid  = threadIdx.x;
  const int bid  = blockIdx.x;           // 8192
  const int b    = bid >> 8;
  const int t0   = (bid & 255) << 1;
  const int w    = tid >> 6;
  const int L    = tid & 63;
  const int quad = L >> 4;
  const int l15  = L & 15;

  // stage the whole 2-t tile: 864 linear uint4 (aligned, contiguous)
  {
    const uint4* src = (const uint4*)(xblk + (size_t)bid * 6912);
    uint4* xs4 = (uint4*)Xs;
    #pragma unroll
    for (int r = 0; r < 4; ++r) {
      int i4 = (r << 8) + tid;
      if (i4 < 864) xs4[i4] = src[i4];
    }
  }

  // zero Zt pad rows 56..63 once (rows 54/55 written zeros every t via Ae pad)
  for (int i = tid; i < 1056; i += 256)
    ((uint32*)(Zt + 56 * ZS))[i] = 0u;

  // persistent step-2 B-frags: W2 row o = w*16+l15, k = kk*32+quad*8
  bf16x8 wf[8];
  #pragma unroll
  for (int kk = 0; kk < 8; ++kk)
    wf[kk] = *(const bf16x8*)(W2 + (((w << 4) + l15) << 8) + (kk << 5) + (quad << 3));

  // step-1 scatter offsets: col pv = n*16+l15 -> Zt[v][p*64 + c0]
  int zoff[14];
  #pragma unroll
  for (int n = 0; n < 14; ++n) {
    int pv = (n << 4) + l15;
    int p = pv / 56;
    int v = pv - p * 56;
    zoff[n] = v * ZS + (p << 6) + (w << 4) + (quad << 2);
  }

  const int oc  = (w << 4) + l15;      // step-2 output channel; step-1 c-row
  const float bsv = bsum[oc];
  float ssum = 0.f, ssq = 0.f;

  __syncthreads();   // Xs staged; Zt pad rows zeroed

  const uint32* XsD = (const uint32*)Xs;

  for (int tt = 0; tt < 2; ++tt) {
    const int t = t0 + tt;

    // ---- step 1: Z[c][pv] = X[c][u] @ Ae[pv][u]^T ----
    // packed row = 27 dwords; u>=54 reads spill into the next row but
    // multiply Ae's zero columns (u 54..63) -> harmless.
    const int xbase = ((tt << 6) + oc) * 27 + (quad << 2);
    union { uint32 u[4]; bf16x8 v; } ua0, ua1;
    ua0.u[0] = XsD[xbase];      ua0.u[1] = XsD[xbase + 1];
    ua0.u[2] = XsD[xbase + 2];  ua0.u[3] = XsD[xbase + 3];
    ua1.u[0] = XsD[xbase + 16]; ua1.u[1] = XsD[xbase + 17];
    ua1.u[2] = XsD[xbase + 18]; ua1.u[3] = XsD[xbase + 19];
    const bf16x8 xa0 = ua0.v, xa1 = ua1.v;

    #pragma unroll
    for (int n = 0; n < 14; ++n) {
      const bf16_t* ar = Ae + (((n << 4) + l15) << 6) + (quad << 3);
      f32x4 acc = {0.f, 0.f, 0.f, 0.f};
      acc = mfma16(xa0, *(const bf16x8*)(ar), acc);
      acc = mfma16(xa1, *(const bf16x8*)(ar + 32), acc);
      uint32* dst = (uint32*)(Zt + zoff[n]);
      dst[0] = pk2(acc[0], acc[1]);
      dst[1] = pk2(acc[2], acc[3]);
    }

    __syncthreads();   // [B1] Zt ready

    // ---- step 2: D[v][o] = Zt[v][K=256] @ W2[o][K]^T, direct stores ----
    const size_t ybase = (size_t)((b << 7) + (t >> 2)) * 13824
                       + (size_t)(t & 3) * 3456 + (size_t)oc * 54;
    #pragma unroll
    for (int mi = 0; mi < 4; ++mi) {
      f32x4 acc = {0.f, 0.f, 0.f, 0.f};
      #pragma unroll
      for (int kk = 0; kk < 8; ++kk) {
        bf16x8 za = *(const bf16x8*)(Zt + ((mi << 4) + l15) * ZS
                                        + (kk << 5) + (quad << 3));
        acc = mfma16(za, wf[kk], acc);
      }
      const int v0 = (mi << 4) + (quad << 2);
      if (v0 + 3 < 54) {
        float y0 = acc[0] + bsv, y1 = acc[1] + bsv, y2 = acc[2] + bsv, y3 = acc[3] + bsv;
        uint32* d = (uint32*)(yprev + ybase + v0);
        d[0] = pk2(y0, y1); d[1] = pk2(y2, y3);
        ssum += y0 + y1 + y2 + y3;
        ssq  += y0 * y0 + y1 * y1 + y2 * y2 + y3 * y3;
      } else if (v0 == 52) {
        float y0 = acc[0] + bsv, y1 = acc[1] + bsv;
        *(uint32*)(yprev + ybase + v0) = pk2(y0, y1);
        ssum += y0 + y1;
        ssq  += y0 * y0 + y1 * y1;
      }
    }

    __syncthreads();   // [B2] Zt reads done -> next tt may rewrite
  }

  // reduce stats across the 4 quads holding the same channel
  ssum += __shfl_xor(ssum, 16); ssq += __shfl_xor(ssq, 16);
  ssum += __shfl_xor(ssum, 32); ssq += __shfl_xor(ssq, 32);
  if (L < 16) {
    float* sb = stats + (bid & 63) * 128;
    atomicAdd(&sb[oc], ssum);
    atomicAdd(&sb[64 + oc], ssq);
  }
}

// ---------------- k_pass1_fp32 (fallback: fp32 x in, fp32 ypre to d_out) ----
#define XSS 72
__global__ __launch_bounds__(256, 3) void k_pass1_fp32(
    const float* __restrict__ x, const bf16_t* __restrict__ W2,
    const bf16_t* __restrict__ Ae, const float* __restrict__ bsum,
    float* __restrict__ yprev, float* __restrict__ stats) {
  __shared__ bf16_t Zt[64 * ZS];
  __shared__ bf16_t Xs[64 * XSS];

  const int tid  = threadIdx.x;
  const int bid  = blockIdx.x;
  const int b    = bid >> 7;
  const int t0   = (bid & 127) << 2;
  const int w    = tid >> 6;
  const int L    = tid & 63;
  const int quad = L >> 4;
  const int l15  = L & 15;

  for (int i = tid; i < 1056; i += 256)
    ((uint32*)(Zt + 56 * ZS))[i] = 0u;

  bf16x8 wf[8];
  #pragma unroll
  for (int kk = 0; kk < 8; ++kk)
    wf[kk] = *(const bf16x8*)(W2 + (((w << 4) + l15) << 8) + (kk << 5) + (quad << 3));

  int zoff[14];
  #pragma unroll
  for (int n = 0; n < 14; ++n) {
    int pv = (n << 4) + l15;
    int p = pv / 56;
    int v = pv - p * 56;
    zoff[n] = v * ZS + (p << 6) + (w << 4) + (quad << 2);
  }

  const int oc  = (w << 4) + l15;
  const float bsv = bsum[oc];
  float ssum = 0.f, ssq = 0.f;

  const int  f2   = tid & 31;
  const bool ldon = f2 < 27;
  const size_t gbase = ((size_t)(b << 6) + (tid >> 5)) * 27648 + ((size_t)f2 << 1);
  uint32* xsd = (uint32*)((char*)Xs + (tid >> 5) * (XSS * 2) + (f2 << 2));

  float2 pf[8];
  #pragma unroll
  for (int j = 0; j < 8; ++j) pf[j] = make_float2(0.f, 0.f);
  if (ldon) {
    #pragma unroll
    for (int j = 0; j < 8; ++j)
      pf[j] = *(const float2*)(x + gbase + (size_t)j * 221184 + (size_t)t0 * 54);
  }

  for (int tt = 0; tt < 4; ++tt) {
    const int t = t0 + tt;
    #pragma unroll
    for (int j = 0; j < 8; ++j) xsd[j * 288] = pk2(pf[j].x, pf[j].y);
    __syncthreads();

    const bf16_t* xr = Xs + oc * XSS;
    bf16x8 xa0 = *(const bf16x8*)(xr + (quad << 3));
    bf16x8 xa1 = *(const bf16x8*)(xr + 32 + (quad << 3));
    #pragma unroll
    for (int n = 0; n < 14; ++n) {
      const bf16_t* ar = Ae + (((n << 4) + l15) << 6) + (quad << 3);
      f32x4 acc = {0.f, 0.f, 0.f, 0.f};
      acc = mfma16(xa0, *(const bf16x8*)(ar), acc);
      acc = mfma16(xa1, *(const bf16x8*)(ar + 32), acc);
      uint32* dst = (uint32*)(Zt + zoff[n]);
      dst[0] = pk2(acc[0], acc[1]);
      dst[1] = pk2(acc[2], acc[3]);
    }
    __syncthreads();

    if (ldon && tt < 3) {
      #pragma unroll
      for (int j = 0; j < 8; ++j)
        pf[j] = *(const float2*)(x + gbase + (size_t)j * 221184 + (size_t)(t + 1) * 54);
    }

    const size_t obase = (((size_t)((b << 6) + oc) << 9) + (size_t)t) * 54;
    #pragma unroll
    for (int mi = 0; mi < 4; ++mi) {
      f32x4 acc = {0.f, 0.f, 0.f, 0.f};
      #pragma unroll
      for (int kk = 0; kk < 8; ++kk) {
        bf16x8 za = *(const bf16x8*)(Zt + ((mi << 4) + l15) * ZS
                                        + (kk << 5) + (quad << 3));
        acc = mfma16(za, wf[kk], acc);
      }
      const int v0 = (mi << 4) + (quad << 2);
      if (v0 + 3 < 54) {
        float y0 = acc[0] + bsv, y1 = acc[1] + bsv, y2 = acc[2] + bsv, y3 = acc[3] + bsv;
        float2* d = (float2*)(yprev + obase + v0);
        d[0] = make_float2(y0, y1); d[1] = make_float2(y2, y3);
        ssum += y0 + y1 + y2 + y3;
        ssq  += y0 * y0 + y1 * y1 + y2 * y2 + y3 * y3;
      } else if (v0 == 52) {
        float y0 = acc[0] + bsv, y1 = acc[1] + bsv;
        *(float2*)(yprev + obase + v0) = make_float2(y0, y1);
        ssum += y0 + y1;
        ssq  += y0 * y0 + y1 * y1;
      }
    }
    __syncthreads();
  }

  ssum += __shfl_xor(ssum, 16); ssq += __shfl_xor(ssq, 16);
  ssum += __shfl_xor(ssum, 32); ssq += __shfl_xor(ssq, 32);
  if (L < 16) {
    float* sb = stats + (bid & 63) * 128;
    atomicAdd(&sb[oc], ssum);
    atomicAdd(&sb[64 + oc], ssq);
  }
}

// ---------------- k_finalize ----------------
__global__ void k_finalize(const float* __restrict__ gamma, const float* __restrict__ beta,
                           const float* __restrict__ stats, float* __restrict__ ac) {
  int o = threadIdx.x;
  if (o >= 64) return;
  float S = 0.f, Q = 0.f;
  for (int buf = 0; buf < 64; ++buf) {
    S += stats[buf * 128 + o];
    Q += stats[buf * 128 + 64 + o];
  }
  const float inv = 1.0f / 884736.0f;
  float mean = S * inv;
  float var  = Q * inv - mean * mean;
  float a = gamma[o] * rsqrtf(var + 1e-5f);
  ac[o] = a;
  ac[64 + o] = beta[o] - mean * a;
}

// ---------------- k_pass2 (linear, yblk layout) ----------------
__global__ __launch_bounds__(256) void k_pass2_lin(
    const float* __restrict__ x, const float* __restrict__ ac,
    const void* __restrict__ yprev, float* __restrict__ out) {
  __shared__ float acS[128];
  const int tid = threadIdx.x;
  const int bid = blockIdx.x;
  if (tid < 128) acS[tid] = ac[tid];
  __syncthreads();

  const int b  = bid >> 7;
  const int t0 = (bid & 127) << 2;
  const uint32* yp = (const uint32*)yprev + (size_t)bid * 6912;
  const float* xb  = x + (size_t)b * 1769472;
  float* ob        = out + (size_t)b * 1769472;

  #pragma unroll 3
  for (int k = 0; k < 27; ++k) {
    const int d  = (k << 8) + tid;       // dword index, < 6912
    const int e0 = d << 1;               // bf16 element index (even)
    const unsigned tt = (unsigned)e0 / 3456u;
    const unsigned r  = (unsigned)e0 - tt * 3456u;
    const unsigned ocv = r / 54u;
    const unsigned v   = r - ocv * 54u;
    const uint32 u = yp[d];
    const float a = acS[ocv], cc = acS[64 + ocv];
    const size_t xi = (size_t)ocv * 27648 + (size_t)(t0 + tt) * 54 + v;
    const float2 xv = *(const float2*)(xb + xi);
    float2 o2;
    o2.x = fmaxf(fmaf(a, bflo(u), cc), 0.f) + xv.x;
    o2.y = fmaxf(fmaf(a, bfhi(u), cc), 0.f) + xv.y;
    *(float2*)(ob + xi) = o2;
  }
}

// ---------------- k_pass2 fallback (legacy linear fp32 in d_out) ----------------
__global__ __launch_bounds__(256) void k_pass2_fb(const float* __restrict__ x,
                                                  const float* __restrict__ ac,
                                                  const float* __restrict__ yprev,
                                                  float* __restrict__ out) {
  const int slab = blockIdx.y;
  const int o = slab & 63;
  const size_t base = (size_t)slab * 27648 + (size_t)(((blockIdx.x << 8) + threadIdx.x) << 2);
  const float a = ac[o], c = ac[64 + o];
  float4 yp = *(const float4*)(yprev + base);
  float4 xv = *(const float4*)(x + base);
  float4 r;
  r.x = fmaxf(fmaf(a, yp.x, c), 0.f) + xv.x;
  r.y = fmaxf(fmaf(a, yp.y, c), 0.f) + xv.y;
  r.z = fmaxf(fmaf(a, yp.z, c), 0.f) + xv.z;
  r.w = fmaxf(fmaf(a, yp.w, c), 0.f) + xv.w;
  *(float4*)(out + base) = r;
}

extern "C" void kernel_launch(void* const* d_in, const int* in_sizes, int n_in,
                              void* d_out, int out_size, void* d_ws, size_t ws_size,
                              hipStream_t stream) {
  const float* x     = (const float*)d_in[0];
  const float* A     = (const float*)d_in[1];
  const float* g     = (const float*)d_in[2];
  const float* W     = (const float*)d_in[3];
  const float* bias  = (const float*)d_in[4];
  const float* gamma = (const float*)d_in[5];
  const float* beta  = (const float*)d_in[6];

  char* ws = (char*)d_ws;
  bf16_t* W2    = (bf16_t*)(ws + 0);       // 32768 B
  bf16_t* Ae    = (bf16_t*)(ws + 32768);   // 28672 B
  float*  bsum  = (float*)(ws + 61440);    // 256 B
  float*  stats = (float*)(ws + 61696);    // 32768 B
  float*  ac    = (float*)(ws + 94464);    // 512 B
  const size_t XBF_OFF   = 98304;
  const size_t XBF_BYTES = (size_t)32 * 64 * 512 * 54 * 2;   // 113246208
  const size_t YP_OFF    = XBF_OFF + XBF_BYTES;              // 113344512
  float* out = (float*)d_out;

  k_prep<<<64, 256, 0, stream>>>(A, g, W, bias, W2, Ae, bsum, stats);

  if (ws_size >= YP_OFF + XBF_BYTES + 4096) {
    bf16_t* xblk = (bf16_t*)(ws + XBF_OFF);
    bf16_t* ypre = (bf16_t*)(ws + YP_OFF);
    k_cast_blk<<<8192, 256, 0, stream>>>(x, xblk);
    k_pass1_blk<<<8192, 256, 0, stream>>>(xblk, W2, Ae, bsum, ypre, stats);
    k_finalize<<<1, 64, 0, stream>>>(gamma, beta, stats, ac);
    k_pass2_lin<<<4096, 256, 0, stream>>>(x, ac, ypre, out);
  } else {
    // fallback: fp32 ypre staged in d_out (legacy layout), pass2 in place
    k_pass1_fp32<<<4096, 256, 0, stream>>>(x, W2, Ae, bsum, out, stats);
    k_finalize<<<1, 64, 0, stream>>>(gamma, beta, stats, ac);
    k_pass2_fb<<<dim3(27, 2048), 256, 0, stream>>>(x, ac, out, out);
  }
}